// Round 7
// baseline (556.728 us; speedup 1.0000x reference)
//
#include <hip/hip_runtime.h>

// Problem constants (shapes fixed by the reference).
#define FIN   128
#define FHID  128
#define FOUT  64
#define FFC   256
#define CHUNK 4096     // edges per binA block

typedef __attribute__((ext_vector_type(8))) short          bf16x8;
typedef __attribute__((ext_vector_type(4))) float          f32x4;
typedef __attribute__((ext_vector_type(8))) unsigned short u16x8;

// ---------------------------------------------------------------------------
// bf16 helpers (raw ushort, RNE rounding)
static __device__ __forceinline__ unsigned short f2bf(float f) {
    unsigned int u = __float_as_uint(f);
    u = (u + 0x7fffu + ((u >> 16) & 1u)) >> 16;
    return (unsigned short)u;
}
static __device__ __forceinline__ float bf2f(unsigned short s) {
    return __uint_as_float(((unsigned int)s) << 16);
}

// ---------------------------------------------------------------------------
// x fp32 -> bf16
__global__ void cvt_bf16_kernel(const float* __restrict__ in,
                                unsigned short* __restrict__ out, long n4) {
    long i = (long)blockIdx.x * blockDim.x + threadIdx.x;
    if (i >= n4) return;
    float4 v = ((const float4*)in)[i];
    ushort4 o = make_ushort4(f2bf(v.x), f2bf(v.y), f2bf(v.z), f2bf(v.w));
    ((ushort4*)out)[i] = o;
}

// all four weights fp32 [K,N] -> bf16 [N,K], one kernel
__global__ void cvt_weights_kernel(
    const float* __restrict__ W1, const float* __restrict__ W2,
    const float* __restrict__ Wf1, const float* __restrict__ Wf2,
    unsigned short* __restrict__ w1t, unsigned short* __restrict__ w2t,
    unsigned short* __restrict__ wf1t, unsigned short* __restrict__ wf2t)
{
    int i = blockIdx.x * blockDim.x + threadIdx.x;
    if (i < 16384) {                       // W1 [128,128]
        int k = i >> 7, n = i & 127;
        w1t[n * 128 + k] = f2bf(W1[i]);
    } else if (i < 24576) {                // W2 [128,64]
        int j = i - 16384; int k = j >> 6, n = j & 63;
        w2t[n * 128 + k] = f2bf(W2[j]);
    } else if (i < 57344) {                // Wf1 [128,256]
        int j = i - 24576; int k = j >> 8, n = j & 255;
        wf1t[n * 128 + k] = f2bf(Wf1[j]);
    } else if (i < 73728) {                // Wf2 [256,64]
        int j = i - 57344; int k = j >> 6, n = j & 63;
        wf2t[n * 256 + k] = f2bf(Wf2[j]);
    }
}

// ---------------------------------------------------------------------------
// Bucketed CSR build. Bucket b = dst >> 8 (256 nodes per bucket).
__global__ __launch_bounds__(256) void hist_kernel(
    const int* __restrict__ dst, int* __restrict__ bhist, int E, int NBK)
{
    __shared__ int h[256];
    int t = threadIdx.x;
    h[t] = 0;
    __syncthreads();
    for (int e = blockIdx.x * blockDim.x + t; e < E; e += gridDim.x * blockDim.x)
        atomicAdd(&h[dst[e] >> 8], 1);
    __syncthreads();
    if (t < NBK && h[t]) atomicAdd(&bhist[t], h[t]);
}

__global__ __launch_bounds__(256) void bscan_kernel(
    const int* __restrict__ bhist, int* __restrict__ bbase,
    int* __restrict__ bcur, int NBK)
{
    __shared__ int tmp[256];
    int t = threadIdx.x;
    int v = (t < NBK) ? bhist[t] : 0;
    tmp[t] = v;
    __syncthreads();
    int acc = v;
    for (int off = 1; off < 256; off <<= 1) {
        int a = (t >= off) ? tmp[t - off] : 0;
        __syncthreads();
        acc += a; tmp[t] = acc;
        __syncthreads();
    }
    if (t < NBK) { bbase[t] = acc - v; bcur[t] = acc - v; }
}

__global__ __launch_bounds__(256) void binA_kernel(
    const int* __restrict__ src, const int* __restrict__ dst,
    int* __restrict__ bcur, uint2* __restrict__ ebuf, int E, int NBK)
{
    __shared__ int hist[256];
    __shared__ int rstart[256];
    __shared__ int lcur[256];
    int t = threadIdx.x;
    hist[t] = 0; lcur[t] = 0;
    __syncthreads();
    int e0 = blockIdx.x * CHUNK;
    int e1 = min(e0 + CHUNK, E);
    for (int e = e0 + t; e < e1; e += 256)
        atomicAdd(&hist[dst[e] >> 8], 1);
    __syncthreads();
    if (t < NBK && hist[t] > 0) rstart[t] = atomicAdd(&bcur[t], hist[t]);
    __syncthreads();
    for (int e = e0 + t; e < e1; e += 256) {
        int s = src[e], d = dst[e];
        int b = d >> 8;
        int pos = atomicAdd(&lcur[b], 1);
        ebuf[rstart[b] + pos] = make_uint2((unsigned)s, (unsigned)d);
    }
}

// Phase B: one block per bucket: node counts -> dinv + rp, place edges into
// col, then (fused) write xs = dinv*x rows for this bucket's nodes.
__global__ __launch_bounds__(256) void binB_kernel(
    const uint2* __restrict__ ebuf, const int* __restrict__ bbase,
    const int* __restrict__ bhist, int* __restrict__ rp,
    int* __restrict__ col, float* __restrict__ dinv,
    const unsigned short* __restrict__ xbf, unsigned short* __restrict__ xs,
    int N)
{
    __shared__ int cnt[256];
    __shared__ int tmp[256];
    __shared__ int ccur[256];
    __shared__ float sdinv[256];
    int b = blockIdx.x;
    int t = threadIdx.x;
    int base = bbase[b];
    int ne = bhist[b];
    cnt[t] = 0;
    __syncthreads();
    for (int e = t; e < ne; e += 256)
        atomicAdd(&cnt[ebuf[base + e].y & 255], 1);
    __syncthreads();
    int node = b * 256 + t;
    int c = cnt[t];
    float di = rsqrtf((float)c + 1.0f);
    sdinv[t] = di;
    if (node < N) dinv[node] = di;
    tmp[t] = c;
    __syncthreads();
    int acc = c;
    for (int off = 1; off < 256; off <<= 1) {
        int a = (t >= off) ? tmp[t - off] : 0;
        __syncthreads();
        acc += a; tmp[t] = acc;
        __syncthreads();
    }
    if (node < N) rp[node] = base + acc;    // inclusive end of node's segment
    ccur[t] = base + acc - c;               // start cursor
    __syncthreads();
    for (int e = t; e < ne; e += 256) {
        uint2 ed = ebuf[base + e];
        int pos = atomicAdd(&ccur[ed.y & 255], 1);
        col[pos] = (int)ed.x;
    }
    // fused: xs rows for this bucket (16 lanes/node, u16x8 each)
    int node0 = b * 256;
    #pragma unroll
    for (int it = 0; it < 16; it++) {
        int nl = it * 16 + (t >> 4);
        int gn = node0 + nl;
        if (gn >= N) continue;
        float d2 = sdinv[nl];
        int fo = (t & 15) << 3;
        u16x8 v = *(const u16x8*)(xbf + (size_t)gn * FIN + fo);
        u16x8 o;
        #pragma unroll
        for (int j = 0; j < 8; j++) o[j] = f2bf(d2 * bf2f(v[j]));
        *(u16x8*)(xs + (size_t)gn * FIN + fo) = o;
    }
}

// ---------------------------------------------------------------------------
// MFMA bf16 GEMM: C[M,Ncol] = A[M,K] @ B[K,Ncol], BT stored [Ncol,K] bf16.
// CF = column fragments per wave (Ncol = CF*16 when grid.x==1 -> A read once).
template <int CF, int CBF, int RELU, int SCALE>
__global__ __launch_bounds__(256) void mfma_gemm(
    const unsigned short* __restrict__ A, const unsigned short* __restrict__ BT,
    const float* __restrict__ bias, const float* __restrict__ rowscale,
    void* __restrict__ Cv, int M, int Ncol, int K)
{
    const int lane = threadIdx.x & 63;
    const int wave = threadIdx.x >> 6;
    const int m = lane & 15;
    const int q = lane >> 4;
    const int rowbase = blockIdx.y * 64 + wave * 16;
    const int row = rowbase + m;
    const int col0 = blockIdx.x * (CF * 16);

    f32x4 acc[CF] = {};

    const unsigned short* arow = A + (size_t)row * K + q * 8;
    const unsigned short* brow = BT + (size_t)(col0 + m) * K + q * 8;

    for (int k0 = 0; k0 < K; k0 += 32) {
        bf16x8 a = {};
        if (row < M) a = *(const bf16x8*)(arow + k0);
        #pragma unroll
        for (int c = 0; c < CF; c++) {
            bf16x8 b = *(const bf16x8*)(brow + (size_t)c * 16 * K + k0);
            acc[c] = __builtin_amdgcn_mfma_f32_16x16x32_bf16(a, b, acc[c], 0, 0, 0);
        }
    }

    float rs[4];
    #pragma unroll
    for (int r = 0; r < 4; r++) {
        int gr = rowbase + q * 4 + r;
        rs[r] = (SCALE && gr < M) ? rowscale[gr] : 1.0f;
    }

    #pragma unroll
    for (int c = 0; c < CF; c++) {
        int gc = col0 + c * 16 + m;
        float bv = bias ? bias[gc] : 0.0f;
        #pragma unroll
        for (int r = 0; r < 4; r++) {
            int gr = rowbase + q * 4 + r;
            if (gr >= M) continue;
            float v = acc[c][r] + bv;
            if (SCALE) v *= rs[r];
            if (RELU) v = fmaxf(v, 0.f);
            if (CBF) ((unsigned short*)Cv)[(size_t)gr * Ncol + gc] = f2bf(v);
            else     ((float*)Cv)[(size_t)gr * Ncol + gc] = v;
        }
    }
}

// ---------------------------------------------------------------------------
// CSR pull, F=128, XCD-pinned feature slices: slice = blockIdx & 3, so with
// round-robin blockIdx->XCD each XCD's L2 only sees one 3.2 MB slice table.
// 4 lanes/node x u16x8 (one 64B line per gather).
__global__ __launch_bounds__(256) void pull1_kernel(
    const unsigned short* __restrict__ xs, const int* __restrict__ rp,
    const int* __restrict__ col, const float* __restrict__ dinv,
    unsigned short* __restrict__ aggx, int N)
{
    int tid = threadIdx.x;
    int b = blockIdx.x;
    int slice = b & 3;
    int node = (b >> 2) * 64 + (tid >> 2);
    if (node >= N) return;
    int f0 = (slice << 5) + ((tid & 3) << 3);
    const unsigned short* base = xs + f0;
    u16x8 own = *(const u16x8*)(base + (size_t)node * FIN);
    float acc[8];
    #pragma unroll
    for (int j = 0; j < 8; j++) acc[j] = bf2f(own[j]);
    int e = node ? rp[node - 1] : 0;
    int end = rp[node];
    for (; e + 4 <= end; e += 4) {
        int s0 = __builtin_nontemporal_load(col + e);
        int s1 = __builtin_nontemporal_load(col + e + 1);
        int s2 = __builtin_nontemporal_load(col + e + 2);
        int s3 = __builtin_nontemporal_load(col + e + 3);
        u16x8 v0 = *(const u16x8*)(base + (size_t)s0 * FIN);
        u16x8 v1 = *(const u16x8*)(base + (size_t)s1 * FIN);
        u16x8 v2 = *(const u16x8*)(base + (size_t)s2 * FIN);
        u16x8 v3 = *(const u16x8*)(base + (size_t)s3 * FIN);
        #pragma unroll
        for (int j = 0; j < 8; j++)
            acc[j] += (bf2f(v0[j]) + bf2f(v1[j])) + (bf2f(v2[j]) + bf2f(v3[j]));
    }
    for (; e < end; e++) {
        int s = __builtin_nontemporal_load(col + e);
        u16x8 v = *(const u16x8*)(base + (size_t)s * FIN);
        #pragma unroll
        for (int j = 0; j < 8; j++) acc[j] += bf2f(v[j]);
    }
    float di = dinv[node];
    u16x8 o;
    #pragma unroll
    for (int j = 0; j < 8; j++) o[j] = f2bf(di * acc[j]);
    *(u16x8*)(aggx + (size_t)node * FIN + f0) = o;
}

// CSR pull, F=64, XCD-pinned slices (slice = blockIdx & 1), fused bias+blend.
__global__ __launch_bounds__(256) void pull2_kernel(
    const unsigned short* __restrict__ t2s, const int* __restrict__ rp,
    const int* __restrict__ col, const float* __restrict__ dinv,
    const float* __restrict__ xfc, const float* __restrict__ b2,
    unsigned short* __restrict__ zbf, int N)
{
    int tid = threadIdx.x;
    int b = blockIdx.x;
    int slice = b & 1;
    int node = (b >> 1) * 64 + (tid >> 2);
    if (node >= N) return;
    int f0 = (slice << 5) + ((tid & 3) << 3);
    const unsigned short* base = t2s + f0;
    u16x8 own = *(const u16x8*)(base + (size_t)node * FOUT);
    float acc[8];
    #pragma unroll
    for (int j = 0; j < 8; j++) acc[j] = bf2f(own[j]);
    int e = node ? rp[node - 1] : 0;
    int end = rp[node];
    for (; e + 4 <= end; e += 4) {
        int s0 = __builtin_nontemporal_load(col + e);
        int s1 = __builtin_nontemporal_load(col + e + 1);
        int s2 = __builtin_nontemporal_load(col + e + 2);
        int s3 = __builtin_nontemporal_load(col + e + 3);
        u16x8 v0 = *(const u16x8*)(base + (size_t)s0 * FOUT);
        u16x8 v1 = *(const u16x8*)(base + (size_t)s1 * FOUT);
        u16x8 v2 = *(const u16x8*)(base + (size_t)s2 * FOUT);
        u16x8 v3 = *(const u16x8*)(base + (size_t)s3 * FOUT);
        #pragma unroll
        for (int j = 0; j < 8; j++)
            acc[j] += (bf2f(v0[j]) + bf2f(v1[j])) + (bf2f(v2[j]) + bf2f(v3[j]));
    }
    for (; e < end; e++) {
        int s = __builtin_nontemporal_load(col + e);
        u16x8 v = *(const u16x8*)(base + (size_t)s * FOUT);
        #pragma unroll
        for (int j = 0; j < 8; j++) acc[j] += bf2f(v[j]);
    }
    float di = dinv[node];
    float4 x0 = *(const float4*)(xfc + (size_t)node * FOUT + f0);
    float4 x1 = *(const float4*)(xfc + (size_t)node * FOUT + f0 + 4);
    float4 bb0 = *(const float4*)(b2 + f0);
    float4 bb1 = *(const float4*)(b2 + f0 + 4);
    float xf[8] = { x0.x, x0.y, x0.z, x0.w, x1.x, x1.y, x1.z, x1.w };
    float bv[8] = { bb0.x, bb0.y, bb0.z, bb0.w, bb1.x, bb1.y, bb1.z, bb1.w };
    u16x8 o;
    #pragma unroll
    for (int j = 0; j < 8; j++)
        o[j] = f2bf(0.5f * (di * acc[j] + bv[j]) + 0.5f * xf[j]);
    *(u16x8*)(zbf + (size_t)node * FOUT + f0) = o;
}

// out[q] = dot(z[a], z[b]) over 64 dims; 8 threads/query, 16B bf16 each.
__global__ void decode_kernel(
    const unsigned short* __restrict__ zbf, const int* __restrict__ eli,
    float* __restrict__ out, int Q)
{
    int tid = blockIdx.x * blockDim.x + threadIdx.x;
    int q = tid >> 3;
    if (q >= Q) return;
    int lane = tid & 7;
    int a = eli[q];
    int b = eli[Q + q];
    u16x8 va = *(const u16x8*)(zbf + (size_t)a * FOUT + lane * 8);
    u16x8 vb = *(const u16x8*)(zbf + (size_t)b * FOUT + lane * 8);
    float s = 0.f;
    #pragma unroll
    for (int j = 0; j < 8; j++) s += bf2f(va[j]) * bf2f(vb[j]);
    s += __shfl_down(s, 4, 8);
    s += __shfl_down(s, 2, 8);
    s += __shfl_down(s, 1, 8);
    if (lane == 0) out[q] = s;
}

// ---------------------------------------------------------------------------
extern "C" void kernel_launch(void* const* d_in, const int* in_sizes, int n_in,
                              void* d_out, int out_size, void* d_ws, size_t ws_size,
                              hipStream_t stream)
{
    const float* x   = (const float*)d_in[0];
    const int*   ei  = (const int*)  d_in[1];
    const int*   eli = (const int*)  d_in[2];
    const float* W1  = (const float*)d_in[3];
    const float* b1  = (const float*)d_in[4];
    const float* W2  = (const float*)d_in[5];
    const float* b2  = (const float*)d_in[6];
    const float* Wf1 = (const float*)d_in[7];
    const float* bf1 = (const float*)d_in[8];
    const float* Wf2 = (const float*)d_in[9];
    const float* bf2 = (const float*)d_in[10];
    float* out = (float*)d_out;

    const int N = in_sizes[0] / FIN;       // 50000
    const int E = in_sizes[1] / 2;         // 1600000
    const int Q = in_sizes[2] / 2;         // 500000
    const int* src = ei;
    const int* dst = ei + E;
    const int NBK = (N + 255) >> 8;        // 196 buckets

    // Workspace layout (bytes; 16B-aligned). Peak ~58 MB.
    // S (25.6 MB) time-multiplexed:
    //   phase FC:   f1 = S[0 : 25.6M]                       (bf16 N*256)
    //   phase CSR:  ebuf = S[12.8M : 25.6M] ; xs = S[0 : 12.8M]
    //   phase L1:   aggx = S[12.8M : 25.6M]; then h1 = S[0 : 12.8M]
    //   phase L2:   t2s = S[12.8M : 19.2M] ; zbf = S[19.2M : 25.6M]
    char* p = (char*)d_ws;
    float* dinv  = (float*)p;            p += (size_t)N * 4;
    int*   rp    = (int*)p;              p += (size_t)(N + 4) * 4;
    int*   bhist = (int*)p;              p += 1024;
    int*   bbase = (int*)p;              p += 1024;
    int*   bcur  = (int*)p;              p += 1024;
    int*   col   = (int*)p;              p += (size_t)E * 4;
    unsigned short* xbf  = (unsigned short*)p; p += (size_t)N * FIN * 2;
    unsigned short* w1t  = (unsigned short*)p; p += FIN * FHID * 2;
    unsigned short* w2t  = (unsigned short*)p; p += FHID * FOUT * 2;
    unsigned short* wf1t = (unsigned short*)p; p += FIN * FFC * 2;
    unsigned short* wf2t = (unsigned short*)p; p += FFC * FOUT * 2;
    float* xfc = (float*)p;              p += (size_t)N * FOUT * 4;
    char*  S   = p;
    unsigned short* f1   = (unsigned short*)S;
    unsigned short* xs   = (unsigned short*)S;
    uint2*          ebuf = (uint2*)(S + (size_t)N * FIN * 2);
    unsigned short* aggx = (unsigned short*)(S + (size_t)N * FIN * 2);
    unsigned short* h1   = (unsigned short*)S;
    unsigned short* t2s  = (unsigned short*)(S + (size_t)N * FIN * 2);
    unsigned short* zbf  = (unsigned short*)(S + (size_t)N * FIN * 2
                                               + (size_t)N * FOUT * 2);

    const int TB = 256;

    // --- converts ---
    {
        long n4 = (long)N * FIN / 4;
        cvt_bf16_kernel<<<(n4 + TB - 1) / TB, TB, 0, stream>>>(x, xbf, n4);
    }
    cvt_weights_kernel<<<(73728 + TB - 1) / TB, TB, 0, stream>>>(
        W1, W2, Wf1, Wf2, w1t, w2t, wf1t, wf2t);

    // --- FC path first (f1 occupies all of S; dead after FC2) ---
    {
        dim3 g(1, (N + 63) / 64);
        mfma_gemm<16, 1, 1, 0><<<g, TB, 0, stream>>>(xbf, wf1t, bf1, nullptr, f1, N, FFC, FIN);
    }
    {
        dim3 g(1, (N + 63) / 64);
        mfma_gemm<4, 0, 0, 0><<<g, TB, 0, stream>>>(f1, wf2t, bf2, nullptr, xfc, N, FOUT, FFC);
    }

    // --- bucketed CSR build (+ fused dinv & xs scaling) ---
    hipMemsetAsync(bhist, 0, 1024, stream);
    hist_kernel<<<1024, TB, 0, stream>>>(dst, bhist, E, NBK);
    bscan_kernel<<<1, TB, 0, stream>>>(bhist, bbase, bcur, NBK);
    binA_kernel<<<(E + CHUNK - 1) / CHUNK, TB, 0, stream>>>(src, dst, bcur, ebuf, E, NBK);
    binB_kernel<<<NBK, TB, 0, stream>>>(ebuf, bbase, bhist, rp, col, dinv, xbf, xs, N);

    // --- GCN layer 1: aggx = dinv*(xs + sum xs) [XCD-sliced]; h1 = relu(aggx@W1+b1) ---
    {
        int nchunk = (N + 63) / 64;
        pull1_kernel<<<nchunk * 4, TB, 0, stream>>>(xs, rp, col, dinv, aggx, N);
    }
    {
        dim3 g(1, (N + 63) / 64);
        mfma_gemm<8, 1, 1, 0><<<g, TB, 0, stream>>>(aggx, w1t, b1, nullptr, h1, N, FHID, FIN);
    }

    // --- GCN layer 2: t2s = dinv*(h1@W2) [bf16]; z = 0.5*(dinv*agg+b2)+0.5*xfc ---
    {
        dim3 g(1, (N + 63) / 64);
        mfma_gemm<4, 1, 0, 1><<<g, TB, 0, stream>>>(h1, w2t, nullptr, dinv, t2s, N, FOUT, FHID);
    }
    {
        int nchunk = (N + 63) / 64;
        pull2_kernel<<<nchunk * 2, TB, 0, stream>>>(t2s, rp, col, dinv, xfc, b2, zbf, N);
    }

    // --- decode ---
    {
        long total = (long)Q * 8;
        decode_kernel<<<(total + TB - 1) / TB, TB, 0, stream>>>(zbf, eli, out, Q);
    }
}

// Round 8
// 528.310 us; speedup vs baseline: 1.0538x; 1.0538x over previous
//
#include <hip/hip_runtime.h>

// Problem constants (shapes fixed by the reference).
#define FIN   128
#define FHID  128
#define FOUT  64
#define FFC   256
#define CHUNK 4096     // edges per binA block

typedef __attribute__((ext_vector_type(8))) short          bf16x8;
typedef __attribute__((ext_vector_type(4))) float          f32x4;
typedef __attribute__((ext_vector_type(8))) unsigned short u16x8;

// ---------------------------------------------------------------------------
// bf16 helpers (raw ushort, RNE rounding)
static __device__ __forceinline__ unsigned short f2bf(float f) {
    unsigned int u = __float_as_uint(f);
    u = (u + 0x7fffu + ((u >> 16) & 1u)) >> 16;
    return (unsigned short)u;
}
static __device__ __forceinline__ float bf2f(unsigned short s) {
    return __uint_as_float(((unsigned int)s) << 16);
}

// ---------------------------------------------------------------------------
// x fp32 -> bf16
__global__ void cvt_bf16_kernel(const float* __restrict__ in,
                                unsigned short* __restrict__ out, long n4) {
    long i = (long)blockIdx.x * blockDim.x + threadIdx.x;
    if (i >= n4) return;
    float4 v = ((const float4*)in)[i];
    ushort4 o = make_ushort4(f2bf(v.x), f2bf(v.y), f2bf(v.z), f2bf(v.w));
    ((ushort4*)out)[i] = o;
}

// all four weights fp32 [K,N] -> bf16 [N,K], one kernel
__global__ void cvt_weights_kernel(
    const float* __restrict__ W1, const float* __restrict__ W2,
    const float* __restrict__ Wf1, const float* __restrict__ Wf2,
    unsigned short* __restrict__ w1t, unsigned short* __restrict__ w2t,
    unsigned short* __restrict__ wf1t, unsigned short* __restrict__ wf2t)
{
    int i = blockIdx.x * blockDim.x + threadIdx.x;
    if (i < 16384) {                       // W1 [128,128]
        int k = i >> 7, n = i & 127;
        w1t[n * 128 + k] = f2bf(W1[i]);
    } else if (i < 24576) {                // W2 [128,64]
        int j = i - 16384; int k = j >> 6, n = j & 63;
        w2t[n * 128 + k] = f2bf(W2[j]);
    } else if (i < 57344) {                // Wf1 [128,256]
        int j = i - 24576; int k = j >> 8, n = j & 255;
        wf1t[n * 128 + k] = f2bf(Wf1[j]);
    } else if (i < 73728) {                // Wf2 [256,64]
        int j = i - 57344; int k = j >> 6, n = j & 63;
        wf2t[n * 256 + k] = f2bf(Wf2[j]);
    }
}

// ---------------------------------------------------------------------------
// Bucketed CSR build. Bucket b = dst >> 8 (256 nodes per bucket).
__global__ __launch_bounds__(256) void hist_kernel(
    const int* __restrict__ dst, int* __restrict__ bhist, int E, int NBK)
{
    __shared__ int h[256];
    int t = threadIdx.x;
    h[t] = 0;
    __syncthreads();
    for (int e = blockIdx.x * blockDim.x + t; e < E; e += gridDim.x * blockDim.x)
        atomicAdd(&h[dst[e] >> 8], 1);
    __syncthreads();
    if (t < NBK && h[t]) atomicAdd(&bhist[t], h[t]);
}

__global__ __launch_bounds__(256) void bscan_kernel(
    const int* __restrict__ bhist, int* __restrict__ bbase,
    int* __restrict__ bcur, int NBK)
{
    __shared__ int tmp[256];
    int t = threadIdx.x;
    int v = (t < NBK) ? bhist[t] : 0;
    tmp[t] = v;
    __syncthreads();
    int acc = v;
    for (int off = 1; off < 256; off <<= 1) {
        int a = (t >= off) ? tmp[t - off] : 0;
        __syncthreads();
        acc += a; tmp[t] = acc;
        __syncthreads();
    }
    if (t < NBK) { bbase[t] = acc - v; bcur[t] = acc - v; }
}

__global__ __launch_bounds__(256) void binA_kernel(
    const int* __restrict__ src, const int* __restrict__ dst,
    int* __restrict__ bcur, uint2* __restrict__ ebuf, int E, int NBK)
{
    __shared__ int hist[256];
    __shared__ int rstart[256];
    __shared__ int lcur[256];
    int t = threadIdx.x;
    hist[t] = 0; lcur[t] = 0;
    __syncthreads();
    int e0 = blockIdx.x * CHUNK;
    int e1 = min(e0 + CHUNK, E);
    for (int e = e0 + t; e < e1; e += 256)
        atomicAdd(&hist[dst[e] >> 8], 1);
    __syncthreads();
    if (t < NBK && hist[t] > 0) rstart[t] = atomicAdd(&bcur[t], hist[t]);
    __syncthreads();
    for (int e = e0 + t; e < e1; e += 256) {
        int s = src[e], d = dst[e];
        int b = d >> 8;
        int pos = atomicAdd(&lcur[b], 1);
        ebuf[rstart[b] + pos] = make_uint2((unsigned)s, (unsigned)d);
    }
}

// Phase B: one block per bucket: node counts -> dinv + rp, place edges into
// col, SORT each node's neighbor list by src (gather locality for the pulls),
// then write xs = dinv*x rows for this bucket's nodes.
__global__ __launch_bounds__(256) void binB_kernel(
    const uint2* __restrict__ ebuf, const int* __restrict__ bbase,
    const int* __restrict__ bhist, int* __restrict__ rp,
    int* __restrict__ col, float* __restrict__ dinv,
    const unsigned short* __restrict__ xbf, unsigned short* __restrict__ xs,
    int N)
{
    __shared__ int cnt[256];
    __shared__ int tmp[256];
    __shared__ int ccur[256];
    __shared__ float sdinv[256];
    __shared__ int sortbuf[256 * 65];      // 65-stride to break bank alignment
    int b = blockIdx.x;
    int t = threadIdx.x;
    int base = bbase[b];
    int ne = bhist[b];
    cnt[t] = 0;
    __syncthreads();
    for (int e = t; e < ne; e += 256)
        atomicAdd(&cnt[ebuf[base + e].y & 255], 1);
    __syncthreads();
    int node = b * 256 + t;
    int c = cnt[t];
    float di = rsqrtf((float)c + 1.0f);
    sdinv[t] = di;
    if (node < N) dinv[node] = di;
    tmp[t] = c;
    __syncthreads();
    int acc = c;
    for (int off = 1; off < 256; off <<= 1) {
        int a = (t >= off) ? tmp[t - off] : 0;
        __syncthreads();
        acc += a; tmp[t] = acc;
        __syncthreads();
    }
    if (node < N) rp[node] = base + acc;    // inclusive end of node's segment
    ccur[t] = base + acc - c;               // start cursor
    __syncthreads();
    for (int e = t; e < ne; e += 256) {
        uint2 ed = ebuf[base + e];
        int pos = atomicAdd(&ccur[ed.y & 255], 1);
        col[pos] = (int)ed.x;
    }
    __syncthreads();
    // sort this node's segment ascending by src (perf-only transform)
    if (c > 1 && c <= 64) {
        int s0 = ccur[t] - c;               // segment start (ccur now = end)
        int* lb = &sortbuf[t * 65];
        for (int j = 0; j < c; j++) lb[j] = col[s0 + j];
        for (int j = 1; j < c; j++) {
            int key = lb[j];
            int k = j - 1;
            while (k >= 0 && lb[k] > key) { lb[k + 1] = lb[k]; k--; }
            lb[k + 1] = key;
        }
        for (int j = 0; j < c; j++) col[s0 + j] = lb[j];
    }
    // fused: xs rows for this bucket (16 lanes/node, u16x8 each)
    int node0 = b * 256;
    #pragma unroll
    for (int it = 0; it < 16; it++) {
        int nl = it * 16 + (t >> 4);
        int gn = node0 + nl;
        if (gn >= N) continue;
        float d2 = sdinv[nl];
        int fo = (t & 15) << 3;
        u16x8 v = *(const u16x8*)(xbf + (size_t)gn * FIN + fo);
        u16x8 o;
        #pragma unroll
        for (int j = 0; j < 8; j++) o[j] = f2bf(d2 * bf2f(v[j]));
        *(u16x8*)(xs + (size_t)gn * FIN + fo) = o;
    }
}

// ---------------------------------------------------------------------------
// MFMA bf16 GEMM: C[M,Ncol] = A[M,K] @ B[K,Ncol], BT stored [Ncol,K] bf16.
// CF = column fragments per wave (Ncol = CF*16 when grid.x==1 -> A read once).
template <int CF, int CBF, int RELU, int SCALE>
__global__ __launch_bounds__(256) void mfma_gemm(
    const unsigned short* __restrict__ A, const unsigned short* __restrict__ BT,
    const float* __restrict__ bias, const float* __restrict__ rowscale,
    void* __restrict__ Cv, int M, int Ncol, int K)
{
    const int lane = threadIdx.x & 63;
    const int wave = threadIdx.x >> 6;
    const int m = lane & 15;
    const int q = lane >> 4;
    const int rowbase = blockIdx.y * 64 + wave * 16;
    const int row = rowbase + m;
    const int col0 = blockIdx.x * (CF * 16);

    f32x4 acc[CF] = {};

    const unsigned short* arow = A + (size_t)row * K + q * 8;
    const unsigned short* brow = BT + (size_t)(col0 + m) * K + q * 8;

    for (int k0 = 0; k0 < K; k0 += 32) {
        bf16x8 a = {};
        if (row < M) a = *(const bf16x8*)(arow + k0);
        #pragma unroll
        for (int c = 0; c < CF; c++) {
            bf16x8 b = *(const bf16x8*)(brow + (size_t)c * 16 * K + k0);
            acc[c] = __builtin_amdgcn_mfma_f32_16x16x32_bf16(a, b, acc[c], 0, 0, 0);
        }
    }

    float rs[4];
    #pragma unroll
    for (int r = 0; r < 4; r++) {
        int gr = rowbase + q * 4 + r;
        rs[r] = (SCALE && gr < M) ? rowscale[gr] : 1.0f;
    }

    #pragma unroll
    for (int c = 0; c < CF; c++) {
        int gc = col0 + c * 16 + m;
        float bv = bias ? bias[gc] : 0.0f;
        #pragma unroll
        for (int r = 0; r < 4; r++) {
            int gr = rowbase + q * 4 + r;
            if (gr >= M) continue;
            float v = acc[c][r] + bv;
            if (SCALE) v *= rs[r];
            if (RELU) v = fmaxf(v, 0.f);
            if (CBF) ((unsigned short*)Cv)[(size_t)gr * Ncol + gc] = f2bf(v);
            else     ((float*)Cv)[(size_t)gr * Ncol + gc] = v;
        }
    }
}

// ---------------------------------------------------------------------------
// CSR pull, F=128, pre-scaled rows, src-sorted lists:
// aggx[i] = di*(xs[i] + sum_s xs[s]).  16 lanes/node, 16B/lane, 4x unroll.
__global__ __launch_bounds__(256) void pull1_kernel(
    const unsigned short* __restrict__ xs, const int* __restrict__ rp,
    const int* __restrict__ col, const float* __restrict__ dinv,
    unsigned short* __restrict__ aggx, int N)
{
    int tid = threadIdx.x;
    int node = blockIdx.x * 16 + (tid >> 4);
    if (node >= N) return;
    int f0 = (tid & 15) << 3;
    const unsigned short* base = xs + f0;
    u16x8 own = *(const u16x8*)(base + (size_t)node * FIN);
    float acc[8];
    #pragma unroll
    for (int j = 0; j < 8; j++) acc[j] = bf2f(own[j]);
    int e = node ? rp[node - 1] : 0;
    int end = rp[node];
    for (; e + 4 <= end; e += 4) {
        int s0 = col[e], s1 = col[e + 1], s2 = col[e + 2], s3 = col[e + 3];
        u16x8 v0 = *(const u16x8*)(base + (size_t)s0 * FIN);
        u16x8 v1 = *(const u16x8*)(base + (size_t)s1 * FIN);
        u16x8 v2 = *(const u16x8*)(base + (size_t)s2 * FIN);
        u16x8 v3 = *(const u16x8*)(base + (size_t)s3 * FIN);
        #pragma unroll
        for (int j = 0; j < 8; j++)
            acc[j] += (bf2f(v0[j]) + bf2f(v1[j])) + (bf2f(v2[j]) + bf2f(v3[j]));
    }
    for (; e < end; e++) {
        u16x8 v = *(const u16x8*)(base + (size_t)col[e] * FIN);
        #pragma unroll
        for (int j = 0; j < 8; j++) acc[j] += bf2f(v[j]);
    }
    float di = dinv[node];
    u16x8 o;
    #pragma unroll
    for (int j = 0; j < 8; j++) o[j] = f2bf(di * acc[j]);
    *(u16x8*)(aggx + (size_t)node * FIN + f0) = o;
}

// CSR pull, F=64, pre-scaled rows, fused bias+blend; bf16 z out.
// 8 lanes/node, 16B/lane, 4x edge unroll.
__global__ __launch_bounds__(256) void pull2_kernel(
    const unsigned short* __restrict__ t2s, const int* __restrict__ rp,
    const int* __restrict__ col, const float* __restrict__ dinv,
    const float* __restrict__ xfc, const float* __restrict__ b2,
    unsigned short* __restrict__ zbf, int N)
{
    int tid = threadIdx.x;
    int node = blockIdx.x * 32 + (tid >> 3);
    if (node >= N) return;
    int f0 = (tid & 7) << 3;
    const unsigned short* base = t2s + f0;
    u16x8 own = *(const u16x8*)(base + (size_t)node * FOUT);
    float acc[8];
    #pragma unroll
    for (int j = 0; j < 8; j++) acc[j] = bf2f(own[j]);
    int e = node ? rp[node - 1] : 0;
    int end = rp[node];
    for (; e + 4 <= end; e += 4) {
        int s0 = col[e], s1 = col[e + 1], s2 = col[e + 2], s3 = col[e + 3];
        u16x8 v0 = *(const u16x8*)(base + (size_t)s0 * FOUT);
        u16x8 v1 = *(const u16x8*)(base + (size_t)s1 * FOUT);
        u16x8 v2 = *(const u16x8*)(base + (size_t)s2 * FOUT);
        u16x8 v3 = *(const u16x8*)(base + (size_t)s3 * FOUT);
        #pragma unroll
        for (int j = 0; j < 8; j++)
            acc[j] += (bf2f(v0[j]) + bf2f(v1[j])) + (bf2f(v2[j]) + bf2f(v3[j]));
    }
    for (; e < end; e++) {
        u16x8 v = *(const u16x8*)(base + (size_t)col[e] * FOUT);
        #pragma unroll
        for (int j = 0; j < 8; j++) acc[j] += bf2f(v[j]);
    }
    float di = dinv[node];
    float4 x0 = *(const float4*)(xfc + (size_t)node * FOUT + f0);
    float4 x1 = *(const float4*)(xfc + (size_t)node * FOUT + f0 + 4);
    float4 bb0 = *(const float4*)(b2 + f0);
    float4 bb1 = *(const float4*)(b2 + f0 + 4);
    float xf[8] = { x0.x, x0.y, x0.z, x0.w, x1.x, x1.y, x1.z, x1.w };
    float bv[8] = { bb0.x, bb0.y, bb0.z, bb0.w, bb1.x, bb1.y, bb1.z, bb1.w };
    u16x8 o;
    #pragma unroll
    for (int j = 0; j < 8; j++)
        o[j] = f2bf(0.5f * (di * acc[j] + bv[j]) + 0.5f * xf[j]);
    *(u16x8*)(zbf + (size_t)node * FOUT + f0) = o;
}

// out[q] = dot(z[a], z[b]) over 64 dims; 8 threads/query, 16B bf16 each.
__global__ void decode_kernel(
    const unsigned short* __restrict__ zbf, const int* __restrict__ eli,
    float* __restrict__ out, int Q)
{
    int tid = blockIdx.x * blockDim.x + threadIdx.x;
    int q = tid >> 3;
    if (q >= Q) return;
    int lane = tid & 7;
    int a = eli[q];
    int b = eli[Q + q];
    u16x8 va = *(const u16x8*)(zbf + (size_t)a * FOUT + lane * 8);
    u16x8 vb = *(const u16x8*)(zbf + (size_t)b * FOUT + lane * 8);
    float s = 0.f;
    #pragma unroll
    for (int j = 0; j < 8; j++) s += bf2f(va[j]) * bf2f(vb[j]);
    s += __shfl_down(s, 4, 8);
    s += __shfl_down(s, 2, 8);
    s += __shfl_down(s, 1, 8);
    if (lane == 0) out[q] = s;
}

// ---------------------------------------------------------------------------
extern "C" void kernel_launch(void* const* d_in, const int* in_sizes, int n_in,
                              void* d_out, int out_size, void* d_ws, size_t ws_size,
                              hipStream_t stream)
{
    const float* x   = (const float*)d_in[0];
    const int*   ei  = (const int*)  d_in[1];
    const int*   eli = (const int*)  d_in[2];
    const float* W1  = (const float*)d_in[3];
    const float* b1  = (const float*)d_in[4];
    const float* W2  = (const float*)d_in[5];
    const float* b2  = (const float*)d_in[6];
    const float* Wf1 = (const float*)d_in[7];
    const float* bf1 = (const float*)d_in[8];
    const float* Wf2 = (const float*)d_in[9];
    const float* bf2 = (const float*)d_in[10];
    float* out = (float*)d_out;

    const int N = in_sizes[0] / FIN;       // 50000
    const int E = in_sizes[1] / 2;         // 1600000
    const int Q = in_sizes[2] / 2;         // 500000
    const int* src = ei;
    const int* dst = ei + E;
    const int NBK = (N + 255) >> 8;        // 196 buckets

    // Workspace layout (bytes; 16B-aligned). Peak ~58 MB.
    // S (25.6 MB) time-multiplexed:
    //   phase FC:   f1 = S[0 : 25.6M]                       (bf16 N*256)
    //   phase CSR:  ebuf = S[12.8M : 25.6M] ; xs = S[0 : 12.8M]
    //   phase L1:   aggx = S[12.8M : 25.6M]; then h1 = S[0 : 12.8M]
    //   phase L2:   t2s = S[12.8M : 19.2M] ; zbf = S[19.2M : 25.6M]
    char* p = (char*)d_ws;
    float* dinv  = (float*)p;            p += (size_t)N * 4;
    int*   rp    = (int*)p;              p += (size_t)(N + 4) * 4;
    int*   bhist = (int*)p;              p += 1024;
    int*   bbase = (int*)p;              p += 1024;
    int*   bcur  = (int*)p;              p += 1024;
    int*   col   = (int*)p;              p += (size_t)E * 4;
    unsigned short* xbf  = (unsigned short*)p; p += (size_t)N * FIN * 2;
    unsigned short* w1t  = (unsigned short*)p; p += FIN * FHID * 2;
    unsigned short* w2t  = (unsigned short*)p; p += FHID * FOUT * 2;
    unsigned short* wf1t = (unsigned short*)p; p += FIN * FFC * 2;
    unsigned short* wf2t = (unsigned short*)p; p += FFC * FOUT * 2;
    float* xfc = (float*)p;              p += (size_t)N * FOUT * 4;
    char*  S   = p;
    unsigned short* f1   = (unsigned short*)S;
    unsigned short* xs   = (unsigned short*)S;
    uint2*          ebuf = (uint2*)(S + (size_t)N * FIN * 2);
    unsigned short* aggx = (unsigned short*)(S + (size_t)N * FIN * 2);
    unsigned short* h1   = (unsigned short*)S;
    unsigned short* t2s  = (unsigned short*)(S + (size_t)N * FIN * 2);
    unsigned short* zbf  = (unsigned short*)(S + (size_t)N * FIN * 2
                                               + (size_t)N * FOUT * 2);

    const int TB = 256;

    // --- converts ---
    {
        long n4 = (long)N * FIN / 4;
        cvt_bf16_kernel<<<(n4 + TB - 1) / TB, TB, 0, stream>>>(x, xbf, n4);
    }
    cvt_weights_kernel<<<(73728 + TB - 1) / TB, TB, 0, stream>>>(
        W1, W2, Wf1, Wf2, w1t, w2t, wf1t, wf2t);

    // --- FC path first (f1 occupies all of S; dead after FC2) ---
    {
        dim3 g(1, (N + 63) / 64);
        mfma_gemm<16, 1, 1, 0><<<g, TB, 0, stream>>>(xbf, wf1t, bf1, nullptr, f1, N, FFC, FIN);
    }
    {
        dim3 g(1, (N + 63) / 64);
        mfma_gemm<4, 0, 0, 0><<<g, TB, 0, stream>>>(f1, wf2t, bf2, nullptr, xfc, N, FOUT, FFC);
    }

    // --- bucketed CSR build (+ per-node src-sort + fused dinv & xs scaling) ---
    hipMemsetAsync(bhist, 0, 1024, stream);
    hist_kernel<<<1024, TB, 0, stream>>>(dst, bhist, E, NBK);
    bscan_kernel<<<1, TB, 0, stream>>>(bhist, bbase, bcur, NBK);
    binA_kernel<<<(E + CHUNK - 1) / CHUNK, TB, 0, stream>>>(src, dst, bcur, ebuf, E, NBK);
    binB_kernel<<<NBK, TB, 0, stream>>>(ebuf, bbase, bhist, rp, col, dinv, xbf, xs, N);

    // --- GCN layer 1: aggx = dinv*(xs + sum xs); h1 = relu(aggx@W1+b1) ---
    pull1_kernel<<<(N + 15) / 16, TB, 0, stream>>>(xs, rp, col, dinv, aggx, N);
    {
        dim3 g(1, (N + 63) / 64);
        mfma_gemm<8, 1, 1, 0><<<g, TB, 0, stream>>>(aggx, w1t, b1, nullptr, h1, N, FHID, FIN);
    }

    // --- GCN layer 2: t2s = dinv*(h1@W2) [bf16]; z = 0.5*(dinv*agg+b2)+0.5*xfc ---
    {
        dim3 g(1, (N + 63) / 64);
        mfma_gemm<4, 1, 0, 1><<<g, TB, 0, stream>>>(h1, w2t, nullptr, dinv, t2s, N, FOUT, FHID);
    }
    pull2_kernel<<<(N + 31) / 32, TB, 0, stream>>>(t2s, rp, col, dinv, xfc, b2, zbf, N);

    // --- decode ---
    {
        long total = (long)Q * 8;
        decode_kernel<<<(total + TB - 1) / TB, TB, 0, stream>>>(zbf, eli, out, Q);
    }
}

// Round 9
// 412.284 us; speedup vs baseline: 1.3504x; 1.2814x over previous
//
#include <hip/hip_runtime.h>

// Problem constants (shapes fixed by the reference).
#define FIN   128
#define FHID  128
#define FOUT  64
#define FFC   256
#define CHUNK 4096     // edges per binA block
#define SORT_CAP 10240 // max edges per bucket for LDS sort (mean 8163, std ~90)

typedef __attribute__((ext_vector_type(8))) short          bf16x8;
typedef __attribute__((ext_vector_type(4))) float          f32x4;
typedef __attribute__((ext_vector_type(8))) unsigned short u16x8;

// ---------------------------------------------------------------------------
// bf16 helpers (raw ushort, RNE rounding)
static __device__ __forceinline__ unsigned short f2bf(float f) {
    unsigned int u = __float_as_uint(f);
    u = (u + 0x7fffu + ((u >> 16) & 1u)) >> 16;
    return (unsigned short)u;
}
static __device__ __forceinline__ float bf2f(unsigned short s) {
    return __uint_as_float(((unsigned int)s) << 16);
}

// ---------------------------------------------------------------------------
// x fp32 -> bf16
__global__ void cvt_bf16_kernel(const float* __restrict__ in,
                                unsigned short* __restrict__ out, long n4) {
    long i = (long)blockIdx.x * blockDim.x + threadIdx.x;
    if (i >= n4) return;
    float4 v = ((const float4*)in)[i];
    ushort4 o = make_ushort4(f2bf(v.x), f2bf(v.y), f2bf(v.z), f2bf(v.w));
    ((ushort4*)out)[i] = o;
}

// all four weights fp32 [K,N] -> bf16 [N,K], one kernel
__global__ void cvt_weights_kernel(
    const float* __restrict__ W1, const float* __restrict__ W2,
    const float* __restrict__ Wf1, const float* __restrict__ Wf2,
    unsigned short* __restrict__ w1t, unsigned short* __restrict__ w2t,
    unsigned short* __restrict__ wf1t, unsigned short* __restrict__ wf2t)
{
    int i = blockIdx.x * blockDim.x + threadIdx.x;
    if (i < 16384) {                       // W1 [128,128]
        int k = i >> 7, n = i & 127;
        w1t[n * 128 + k] = f2bf(W1[i]);
    } else if (i < 24576) {                // W2 [128,64]
        int j = i - 16384; int k = j >> 6, n = j & 63;
        w2t[n * 128 + k] = f2bf(W2[j]);
    } else if (i < 57344) {                // Wf1 [128,256]
        int j = i - 24576; int k = j >> 8, n = j & 255;
        wf1t[n * 128 + k] = f2bf(Wf1[j]);
    } else if (i < 73728) {                // Wf2 [256,64]
        int j = i - 57344; int k = j >> 6, n = j & 63;
        wf2t[n * 256 + k] = f2bf(Wf2[j]);
    }
}

// ---------------------------------------------------------------------------
// Bucketed CSR build. Bucket b = dst >> 8 (256 nodes per bucket).
__global__ __launch_bounds__(256) void hist_kernel(
    const int* __restrict__ dst, int* __restrict__ bhist, int E, int NBK)
{
    __shared__ int h[256];
    int t = threadIdx.x;
    h[t] = 0;
    __syncthreads();
    for (int e = blockIdx.x * blockDim.x + t; e < E; e += gridDim.x * blockDim.x)
        atomicAdd(&h[dst[e] >> 8], 1);
    __syncthreads();
    if (t < NBK && h[t]) atomicAdd(&bhist[t], h[t]);
}

__global__ __launch_bounds__(256) void bscan_kernel(
    const int* __restrict__ bhist, int* __restrict__ bbase,
    int* __restrict__ bcur, int NBK)
{
    __shared__ int tmp[256];
    int t = threadIdx.x;
    int v = (t < NBK) ? bhist[t] : 0;
    tmp[t] = v;
    __syncthreads();
    int acc = v;
    for (int off = 1; off < 256; off <<= 1) {
        int a = (t >= off) ? tmp[t - off] : 0;
        __syncthreads();
        acc += a; tmp[t] = acc;
        __syncthreads();
    }
    if (t < NBK) { bbase[t] = acc - v; bcur[t] = acc - v; }
}

__global__ __launch_bounds__(256) void binA_kernel(
    const int* __restrict__ src, const int* __restrict__ dst,
    int* __restrict__ bcur, uint2* __restrict__ ebuf, int E, int NBK)
{
    __shared__ int hist[256];
    __shared__ int rstart[256];
    __shared__ int lcur[256];
    int t = threadIdx.x;
    hist[t] = 0; lcur[t] = 0;
    __syncthreads();
    int e0 = blockIdx.x * CHUNK;
    int e1 = min(e0 + CHUNK, E);
    for (int e = e0 + t; e < e1; e += 256)
        atomicAdd(&hist[dst[e] >> 8], 1);
    __syncthreads();
    if (t < NBK && hist[t] > 0) rstart[t] = atomicAdd(&bcur[t], hist[t]);
    __syncthreads();
    for (int e = e0 + t; e < e1; e += 256) {
        int s = src[e], d = dst[e];
        int b = d >> 8;
        int pos = atomicAdd(&lcur[b], 1);
        ebuf[rstart[b] + pos] = make_uint2((unsigned)s, (unsigned)d);
    }
}

// Phase B: one block per bucket. Node counts -> dinv + rp; then a parallel
// counting sort of the bucket's edges by src>>8 (coarse src order = gather
// locality for the pulls); drain into col via per-node cursors in barriered
// 256-edge windows; finally write xs = dinv*x rows for this bucket.
__global__ __launch_bounds__(256) void binB_kernel(
    const uint2* __restrict__ ebuf, const int* __restrict__ bbase,
    const int* __restrict__ bhist, int* __restrict__ rp,
    int* __restrict__ col, float* __restrict__ dinv,
    const unsigned short* __restrict__ xbf, unsigned short* __restrict__ xs,
    int N)
{
    __shared__ int cnt[256];
    __shared__ int tmp[256];
    __shared__ int ccur[256];
    __shared__ int scur[256];          // src-bucket cursors
    __shared__ float sdinv[256];
    __shared__ unsigned int skey[SORT_CAP];
    int b = blockIdx.x;
    int t = threadIdx.x;
    int base = bbase[b];
    int ne = bhist[b];
    cnt[t] = 0; scur[t] = 0;
    __syncthreads();
    // count local dst + src buckets
    for (int e = t; e < ne; e += 256) {
        uint2 ed = ebuf[base + e];
        atomicAdd(&cnt[ed.y & 255], 1);
        atomicAdd(&scur[ed.x >> 8], 1);
    }
    __syncthreads();
    int node = b * 256 + t;
    int c = cnt[t];
    float di = rsqrtf((float)c + 1.0f);
    sdinv[t] = di;
    if (node < N) dinv[node] = di;
    tmp[t] = c;
    __syncthreads();
    int acc = c;
    for (int off = 1; off < 256; off <<= 1) {
        int a = (t >= off) ? tmp[t - off] : 0;
        __syncthreads();
        acc += a; tmp[t] = acc;
        __syncthreads();
    }
    if (node < N) rp[node] = base + acc;    // inclusive end of node's segment
    ccur[t] = base + acc - c;               // start cursor
    __syncthreads();
    // exclusive scan of src-bucket counts -> scur cursors
    int sv = scur[t];
    tmp[t] = sv;
    __syncthreads();
    int sacc = sv;
    for (int off = 1; off < 256; off <<= 1) {
        int a = (t >= off) ? tmp[t - off] : 0;
        __syncthreads();
        sacc += a; tmp[t] = sacc;
        __syncthreads();
    }
    scur[t] = sacc - sv;
    __syncthreads();
    if (ne <= SORT_CAP) {
        // counting-scatter by src>>8 into skey (coarse src-sorted order)
        for (int e = t; e < ne; e += 256) {
            uint2 ed = ebuf[base + e];
            int pos = atomicAdd(&scur[ed.x >> 8], 1);
            skey[pos] = (ed.x << 8) | (ed.y & 255);
        }
        __syncthreads();
        // drain to col in order, one 256-edge window at a time
        for (int w = 0; w < ne; w += 256) {
            int e = w + t;
            if (e < ne) {
                unsigned int k = skey[e];
                int pos = atomicAdd(&ccur[k & 255], 1);
                col[pos] = (int)(k >> 8);
            }
            __syncthreads();
        }
    } else {
        for (int e = t; e < ne; e += 256) {
            uint2 ed = ebuf[base + e];
            int pos = atomicAdd(&ccur[ed.y & 255], 1);
            col[pos] = (int)ed.x;
        }
        __syncthreads();
    }
    // fused: xs rows for this bucket (16 lanes/node, u16x8 each)
    int node0 = b * 256;
    #pragma unroll
    for (int it = 0; it < 16; it++) {
        int nl = it * 16 + (t >> 4);
        int gn = node0 + nl;
        if (gn >= N) continue;
        float d2 = sdinv[nl];
        int fo = (t & 15) << 3;
        u16x8 v = *(const u16x8*)(xbf + (size_t)gn * FIN + fo);
        u16x8 o;
        #pragma unroll
        for (int j = 0; j < 8; j++) o[j] = f2bf(d2 * bf2f(v[j]));
        *(u16x8*)(xs + (size_t)gn * FIN + fo) = o;
    }
}

// ---------------------------------------------------------------------------
// MFMA bf16 GEMM: C[M,Ncol] = A[M,K] @ B[K,Ncol], BT stored [Ncol,K] bf16.
// CF = column fragments per wave (Ncol = CF*16 when grid.x==1 -> A read once).
template <int CF, int CBF, int RELU, int SCALE>
__global__ __launch_bounds__(256) void mfma_gemm(
    const unsigned short* __restrict__ A, const unsigned short* __restrict__ BT,
    const float* __restrict__ bias, const float* __restrict__ rowscale,
    void* __restrict__ Cv, int M, int Ncol, int K)
{
    const int lane = threadIdx.x & 63;
    const int wave = threadIdx.x >> 6;
    const int m = lane & 15;
    const int q = lane >> 4;
    const int rowbase = blockIdx.y * 64 + wave * 16;
    const int row = rowbase + m;
    const int col0 = blockIdx.x * (CF * 16);

    f32x4 acc[CF] = {};

    const unsigned short* arow = A + (size_t)row * K + q * 8;
    const unsigned short* brow = BT + (size_t)(col0 + m) * K + q * 8;

    for (int k0 = 0; k0 < K; k0 += 32) {
        bf16x8 a = {};
        if (row < M) a = *(const bf16x8*)(arow + k0);
        #pragma unroll
        for (int c = 0; c < CF; c++) {
            bf16x8 b = *(const bf16x8*)(brow + (size_t)c * 16 * K + k0);
            acc[c] = __builtin_amdgcn_mfma_f32_16x16x32_bf16(a, b, acc[c], 0, 0, 0);
        }
    }

    float rs[4];
    #pragma unroll
    for (int r = 0; r < 4; r++) {
        int gr = rowbase + q * 4 + r;
        rs[r] = (SCALE && gr < M) ? rowscale[gr] : 1.0f;
    }

    #pragma unroll
    for (int c = 0; c < CF; c++) {
        int gc = col0 + c * 16 + m;
        float bv = bias ? bias[gc] : 0.0f;
        #pragma unroll
        for (int r = 0; r < 4; r++) {
            int gr = rowbase + q * 4 + r;
            if (gr >= M) continue;
            float v = acc[c][r] + bv;
            if (SCALE) v *= rs[r];
            if (RELU) v = fmaxf(v, 0.f);
            if (CBF) ((unsigned short*)Cv)[(size_t)gr * Ncol + gc] = f2bf(v);
            else     ((float*)Cv)[(size_t)gr * Ncol + gc] = v;
        }
    }
}

// ---------------------------------------------------------------------------
// CSR pull, F=128, pre-scaled rows, src-sorted lists:
// aggx[i] = di*(xs[i] + sum_s xs[s]).  16 lanes/node, 16B/lane, 4x unroll.
__global__ __launch_bounds__(256) void pull1_kernel(
    const unsigned short* __restrict__ xs, const int* __restrict__ rp,
    const int* __restrict__ col, const float* __restrict__ dinv,
    unsigned short* __restrict__ aggx, int N)
{
    int tid = threadIdx.x;
    int node = blockIdx.x * 16 + (tid >> 4);
    if (node >= N) return;
    int f0 = (tid & 15) << 3;
    const unsigned short* base = xs + f0;
    u16x8 own = *(const u16x8*)(base + (size_t)node * FIN);
    float acc[8];
    #pragma unroll
    for (int j = 0; j < 8; j++) acc[j] = bf2f(own[j]);
    int e = node ? rp[node - 1] : 0;
    int end = rp[node];
    for (; e + 4 <= end; e += 4) {
        int s0 = col[e], s1 = col[e + 1], s2 = col[e + 2], s3 = col[e + 3];
        u16x8 v0 = *(const u16x8*)(base + (size_t)s0 * FIN);
        u16x8 v1 = *(const u16x8*)(base + (size_t)s1 * FIN);
        u16x8 v2 = *(const u16x8*)(base + (size_t)s2 * FIN);
        u16x8 v3 = *(const u16x8*)(base + (size_t)s3 * FIN);
        #pragma unroll
        for (int j = 0; j < 8; j++)
            acc[j] += (bf2f(v0[j]) + bf2f(v1[j])) + (bf2f(v2[j]) + bf2f(v3[j]));
    }
    for (; e < end; e++) {
        u16x8 v = *(const u16x8*)(base + (size_t)col[e] * FIN);
        #pragma unroll
        for (int j = 0; j < 8; j++) acc[j] += bf2f(v[j]);
    }
    float di = dinv[node];
    u16x8 o;
    #pragma unroll
    for (int j = 0; j < 8; j++) o[j] = f2bf(di * acc[j]);
    *(u16x8*)(aggx + (size_t)node * FIN + f0) = o;
}

// CSR pull, F=64, pre-scaled rows, fused bias+blend; bf16 z out.
// 8 lanes/node, 16B/lane, 4x edge unroll.
__global__ __launch_bounds__(256) void pull2_kernel(
    const unsigned short* __restrict__ t2s, const int* __restrict__ rp,
    const int* __restrict__ col, const float* __restrict__ dinv,
    const float* __restrict__ xfc, const float* __restrict__ b2,
    unsigned short* __restrict__ zbf, int N)
{
    int tid = threadIdx.x;
    int node = blockIdx.x * 32 + (tid >> 3);
    if (node >= N) return;
    int f0 = (tid & 7) << 3;
    const unsigned short* base = t2s + f0;
    u16x8 own = *(const u16x8*)(base + (size_t)node * FOUT);
    float acc[8];
    #pragma unroll
    for (int j = 0; j < 8; j++) acc[j] = bf2f(own[j]);
    int e = node ? rp[node - 1] : 0;
    int end = rp[node];
    for (; e + 4 <= end; e += 4) {
        int s0 = col[e], s1 = col[e + 1], s2 = col[e + 2], s3 = col[e + 3];
        u16x8 v0 = *(const u16x8*)(base + (size_t)s0 * FOUT);
        u16x8 v1 = *(const u16x8*)(base + (size_t)s1 * FOUT);
        u16x8 v2 = *(const u16x8*)(base + (size_t)s2 * FOUT);
        u16x8 v3 = *(const u16x8*)(base + (size_t)s3 * FOUT);
        #pragma unroll
        for (int j = 0; j < 8; j++)
            acc[j] += (bf2f(v0[j]) + bf2f(v1[j])) + (bf2f(v2[j]) + bf2f(v3[j]));
    }
    for (; e < end; e++) {
        u16x8 v = *(const u16x8*)(base + (size_t)col[e] * FOUT);
        #pragma unroll
        for (int j = 0; j < 8; j++) acc[j] += bf2f(v[j]);
    }
    float di = dinv[node];
    float4 x0 = *(const float4*)(xfc + (size_t)node * FOUT + f0);
    float4 x1 = *(const float4*)(xfc + (size_t)node * FOUT + f0 + 4);
    float4 bb0 = *(const float4*)(b2 + f0);
    float4 bb1 = *(const float4*)(b2 + f0 + 4);
    float xf[8] = { x0.x, x0.y, x0.z, x0.w, x1.x, x1.y, x1.z, x1.w };
    float bv[8] = { bb0.x, bb0.y, bb0.z, bb0.w, bb1.x, bb1.y, bb1.z, bb1.w };
    u16x8 o;
    #pragma unroll
    for (int j = 0; j < 8; j++)
        o[j] = f2bf(0.5f * (di * acc[j] + bv[j]) + 0.5f * xf[j]);
    *(u16x8*)(zbf + (size_t)node * FOUT + f0) = o;
}

// out[q] = dot(z[a], z[b]) over 64 dims; 8 threads/query, 16B bf16 each.
__global__ void decode_kernel(
    const unsigned short* __restrict__ zbf, const int* __restrict__ eli,
    float* __restrict__ out, int Q)
{
    int tid = blockIdx.x * blockDim.x + threadIdx.x;
    int q = tid >> 3;
    if (q >= Q) return;
    int lane = tid & 7;
    int a = eli[q];
    int b = eli[Q + q];
    u16x8 va = *(const u16x8*)(zbf + (size_t)a * FOUT + lane * 8);
    u16x8 vb = *(const u16x8*)(zbf + (size_t)b * FOUT + lane * 8);
    float s = 0.f;
    #pragma unroll
    for (int j = 0; j < 8; j++) s += bf2f(va[j]) * bf2f(vb[j]);
    s += __shfl_down(s, 4, 8);
    s += __shfl_down(s, 2, 8);
    s += __shfl_down(s, 1, 8);
    if (lane == 0) out[q] = s;
}

// ---------------------------------------------------------------------------
extern "C" void kernel_launch(void* const* d_in, const int* in_sizes, int n_in,
                              void* d_out, int out_size, void* d_ws, size_t ws_size,
                              hipStream_t stream)
{
    const float* x   = (const float*)d_in[0];
    const int*   ei  = (const int*)  d_in[1];
    const int*   eli = (const int*)  d_in[2];
    const float* W1  = (const float*)d_in[3];
    const float* b1  = (const float*)d_in[4];
    const float* W2  = (const float*)d_in[5];
    const float* b2  = (const float*)d_in[6];
    const float* Wf1 = (const float*)d_in[7];
    const float* bf1 = (const float*)d_in[8];
    const float* Wf2 = (const float*)d_in[9];
    const float* bf2 = (const float*)d_in[10];
    float* out = (float*)d_out;

    const int N = in_sizes[0] / FIN;       // 50000
    const int E = in_sizes[1] / 2;         // 1600000
    const int Q = in_sizes[2] / 2;         // 500000
    const int* src = ei;
    const int* dst = ei + E;
    const int NBK = (N + 255) >> 8;        // 196 buckets

    // Workspace layout (bytes; 16B-aligned). Peak ~58 MB.
    // S (25.6 MB) time-multiplexed:
    //   phase FC:   f1 = S[0 : 25.6M]                       (bf16 N*256)
    //   phase CSR:  ebuf = S[12.8M : 25.6M] ; xs = S[0 : 12.8M]
    //   phase L1:   aggx = S[12.8M : 25.6M]; then h1 = S[0 : 12.8M]
    //   phase L2:   t2s = S[12.8M : 19.2M] ; zbf = S[19.2M : 25.6M]
    char* p = (char*)d_ws;
    float* dinv  = (float*)p;            p += (size_t)N * 4;
    int*   rp    = (int*)p;              p += (size_t)(N + 4) * 4;
    int*   bhist = (int*)p;              p += 1024;
    int*   bbase = (int*)p;              p += 1024;
    int*   bcur  = (int*)p;              p += 1024;
    int*   col   = (int*)p;              p += (size_t)E * 4;
    unsigned short* xbf  = (unsigned short*)p; p += (size_t)N * FIN * 2;
    unsigned short* w1t  = (unsigned short*)p; p += FIN * FHID * 2;
    unsigned short* w2t  = (unsigned short*)p; p += FHID * FOUT * 2;
    unsigned short* wf1t = (unsigned short*)p; p += FIN * FFC * 2;
    unsigned short* wf2t = (unsigned short*)p; p += FFC * FOUT * 2;
    float* xfc = (float*)p;              p += (size_t)N * FOUT * 4;
    char*  S   = p;
    unsigned short* f1   = (unsigned short*)S;
    unsigned short* xs   = (unsigned short*)S;
    uint2*          ebuf = (uint2*)(S + (size_t)N * FIN * 2);
    unsigned short* aggx = (unsigned short*)(S + (size_t)N * FIN * 2);
    unsigned short* h1   = (unsigned short*)S;
    unsigned short* t2s  = (unsigned short*)(S + (size_t)N * FIN * 2);
    unsigned short* zbf  = (unsigned short*)(S + (size_t)N * FIN * 2
                                               + (size_t)N * FOUT * 2);

    const int TB = 256;

    // --- converts ---
    {
        long n4 = (long)N * FIN / 4;
        cvt_bf16_kernel<<<(n4 + TB - 1) / TB, TB, 0, stream>>>(x, xbf, n4);
    }
    cvt_weights_kernel<<<(73728 + TB - 1) / TB, TB, 0, stream>>>(
        W1, W2, Wf1, Wf2, w1t, w2t, wf1t, wf2t);

    // --- FC path first (f1 occupies all of S; dead after FC2) ---
    {
        dim3 g(1, (N + 63) / 64);
        mfma_gemm<16, 1, 1, 0><<<g, TB, 0, stream>>>(xbf, wf1t, bf1, nullptr, f1, N, FFC, FIN);
    }
    {
        dim3 g(1, (N + 63) / 64);
        mfma_gemm<4, 0, 0, 0><<<g, TB, 0, stream>>>(f1, wf2t, bf2, nullptr, xfc, N, FOUT, FFC);
    }

    // --- bucketed CSR build (+ coarse src-sort + fused dinv & xs scaling) ---
    hipMemsetAsync(bhist, 0, 1024, stream);
    hist_kernel<<<1024, TB, 0, stream>>>(dst, bhist, E, NBK);
    bscan_kernel<<<1, TB, 0, stream>>>(bhist, bbase, bcur, NBK);
    binA_kernel<<<(E + CHUNK - 1) / CHUNK, TB, 0, stream>>>(src, dst, bcur, ebuf, E, NBK);
    binB_kernel<<<NBK, TB, 0, stream>>>(ebuf, bbase, bhist, rp, col, dinv, xbf, xs, N);

    // --- GCN layer 1: aggx = dinv*(xs + sum xs); h1 = relu(aggx@W1+b1) ---
    pull1_kernel<<<(N + 15) / 16, TB, 0, stream>>>(xs, rp, col, dinv, aggx, N);
    {
        dim3 g(1, (N + 63) / 64);
        mfma_gemm<8, 1, 1, 0><<<g, TB, 0, stream>>>(aggx, w1t, b1, nullptr, h1, N, FHID, FIN);
    }

    // --- GCN layer 2: t2s = dinv*(h1@W2) [bf16]; z = 0.5*(dinv*agg+b2)+0.5*xfc ---
    {
        dim3 g(1, (N + 63) / 64);
        mfma_gemm<4, 1, 0, 1><<<g, TB, 0, stream>>>(h1, w2t, nullptr, dinv, t2s, N, FOUT, FHID);
    }
    pull2_kernel<<<(N + 31) / 32, TB, 0, stream>>>(t2s, rp, col, dinv, xfc, b2, zbf, N);

    // --- decode ---
    {
        long total = (long)Q * 8;
        decode_kernel<<<(total + TB - 1) / TB, TB, 0, stream>>>(zbf, eli, out, Q);
    }
}

// Round 10
// 389.061 us; speedup vs baseline: 1.4310x; 1.0597x over previous
//
#include <hip/hip_runtime.h>

// Problem constants (shapes fixed by the reference).
#define FIN   128
#define FHID  128
#define FOUT  64
#define FFC   256
#define CHUNK 4096     // edges per binA block
#define SORT_CAP 10240 // max edges per bucket for LDS sort (mean 8163, std ~90)

typedef __attribute__((ext_vector_type(8))) short          bf16x8;
typedef __attribute__((ext_vector_type(4))) float          f32x4;
typedef __attribute__((ext_vector_type(8))) unsigned short u16x8;

// ---------------------------------------------------------------------------
// bf16 helpers (raw ushort, RNE rounding)
static __device__ __forceinline__ unsigned short f2bf(float f) {
    unsigned int u = __float_as_uint(f);
    u = (u + 0x7fffu + ((u >> 16) & 1u)) >> 16;
    return (unsigned short)u;
}
static __device__ __forceinline__ float bf2f(unsigned short s) {
    return __uint_as_float(((unsigned int)s) << 16);
}

// ---------------------------------------------------------------------------
// x fp32 -> bf16
__global__ void cvt_bf16_kernel(const float* __restrict__ in,
                                unsigned short* __restrict__ out, long n4) {
    long i = (long)blockIdx.x * blockDim.x + threadIdx.x;
    if (i >= n4) return;
    float4 v = ((const float4*)in)[i];
    ushort4 o = make_ushort4(f2bf(v.x), f2bf(v.y), f2bf(v.z), f2bf(v.w));
    ((ushort4*)out)[i] = o;
}

// all four weights fp32 [K,N] -> bf16 [N,K], one kernel
__global__ void cvt_weights_kernel(
    const float* __restrict__ W1, const float* __restrict__ W2,
    const float* __restrict__ Wf1, const float* __restrict__ Wf2,
    unsigned short* __restrict__ w1t, unsigned short* __restrict__ w2t,
    unsigned short* __restrict__ wf1t, unsigned short* __restrict__ wf2t)
{
    int i = blockIdx.x * blockDim.x + threadIdx.x;
    if (i < 16384) {                       // W1 [128,128]
        int k = i >> 7, n = i & 127;
        w1t[n * 128 + k] = f2bf(W1[i]);
    } else if (i < 24576) {                // W2 [128,64]
        int j = i - 16384; int k = j >> 6, n = j & 63;
        w2t[n * 128 + k] = f2bf(W2[j]);
    } else if (i < 57344) {                // Wf1 [128,256]
        int j = i - 24576; int k = j >> 8, n = j & 255;
        wf1t[n * 128 + k] = f2bf(Wf1[j]);
    } else if (i < 73728) {                // Wf2 [256,64]
        int j = i - 57344; int k = j >> 6, n = j & 63;
        wf2t[n * 256 + k] = f2bf(Wf2[j]);
    }
}

// ---------------------------------------------------------------------------
// Bucketed CSR build. Bucket b = dst >> 8 (256 nodes per bucket).
__global__ __launch_bounds__(256) void hist_kernel(
    const int* __restrict__ dst, int* __restrict__ bhist, int E, int NBK)
{
    __shared__ int h[256];
    int t = threadIdx.x;
    h[t] = 0;
    __syncthreads();
    for (int e = blockIdx.x * blockDim.x + t; e < E; e += gridDim.x * blockDim.x)
        atomicAdd(&h[dst[e] >> 8], 1);
    __syncthreads();
    if (t < NBK && h[t]) atomicAdd(&bhist[t], h[t]);
}

__global__ __launch_bounds__(256) void bscan_kernel(
    const int* __restrict__ bhist, int* __restrict__ bbase,
    int* __restrict__ bcur, int NBK)
{
    __shared__ int tmp[256];
    int t = threadIdx.x;
    int v = (t < NBK) ? bhist[t] : 0;
    tmp[t] = v;
    __syncthreads();
    int acc = v;
    for (int off = 1; off < 256; off <<= 1) {
        int a = (t >= off) ? tmp[t - off] : 0;
        __syncthreads();
        acc += a; tmp[t] = acc;
        __syncthreads();
    }
    if (t < NBK) { bbase[t] = acc - v; bcur[t] = acc - v; }
}

__global__ __launch_bounds__(256) void binA_kernel(
    const int* __restrict__ src, const int* __restrict__ dst,
    int* __restrict__ bcur, uint2* __restrict__ ebuf, int E, int NBK)
{
    __shared__ int hist[256];
    __shared__ int rstart[256];
    __shared__ int lcur[256];
    int t = threadIdx.x;
    hist[t] = 0; lcur[t] = 0;
    __syncthreads();
    int e0 = blockIdx.x * CHUNK;
    int e1 = min(e0 + CHUNK, E);
    for (int e = e0 + t; e < e1; e += 256)
        atomicAdd(&hist[dst[e] >> 8], 1);
    __syncthreads();
    if (t < NBK && hist[t] > 0) rstart[t] = atomicAdd(&bcur[t], hist[t]);
    __syncthreads();
    for (int e = e0 + t; e < e1; e += 256) {
        int s = src[e], d = dst[e];
        int b = d >> 8;
        int pos = atomicAdd(&lcur[b], 1);
        ebuf[rstart[b] + pos] = make_uint2((unsigned)s, (unsigned)d);
    }
}

// Phase B: one block per bucket. Node counts -> dinv + rp; parallel counting
// sort by src>>8 (coarse src order = gather locality); drain into col in
// barriered windows; write xs = dinv*x rows for this bucket.
__global__ __launch_bounds__(256) void binB_kernel(
    const uint2* __restrict__ ebuf, const int* __restrict__ bbase,
    const int* __restrict__ bhist, int* __restrict__ rp,
    int* __restrict__ col, float* __restrict__ dinv,
    const unsigned short* __restrict__ xbf, unsigned short* __restrict__ xs,
    int N)
{
    __shared__ int cnt[256];
    __shared__ int tmp[256];
    __shared__ int ccur[256];
    __shared__ int scur[256];          // src-bucket cursors
    __shared__ float sdinv[256];
    __shared__ unsigned int skey[SORT_CAP];
    int b = blockIdx.x;
    int t = threadIdx.x;
    int base = bbase[b];
    int ne = bhist[b];
    cnt[t] = 0; scur[t] = 0;
    __syncthreads();
    for (int e = t; e < ne; e += 256) {
        uint2 ed = ebuf[base + e];
        atomicAdd(&cnt[ed.y & 255], 1);
        atomicAdd(&scur[ed.x >> 8], 1);
    }
    __syncthreads();
    int node = b * 256 + t;
    int c = cnt[t];
    float di = rsqrtf((float)c + 1.0f);
    sdinv[t] = di;
    if (node < N) dinv[node] = di;
    tmp[t] = c;
    __syncthreads();
    int acc = c;
    for (int off = 1; off < 256; off <<= 1) {
        int a = (t >= off) ? tmp[t - off] : 0;
        __syncthreads();
        acc += a; tmp[t] = acc;
        __syncthreads();
    }
    if (node < N) rp[node] = base + acc;    // inclusive end of node's segment
    ccur[t] = base + acc - c;               // start cursor
    __syncthreads();
    int sv = scur[t];
    tmp[t] = sv;
    __syncthreads();
    int sacc = sv;
    for (int off = 1; off < 256; off <<= 1) {
        int a = (t >= off) ? tmp[t - off] : 0;
        __syncthreads();
        sacc += a; tmp[t] = sacc;
        __syncthreads();
    }
    scur[t] = sacc - sv;
    __syncthreads();
    if (ne <= SORT_CAP) {
        for (int e = t; e < ne; e += 256) {
            uint2 ed = ebuf[base + e];
            int pos = atomicAdd(&scur[ed.x >> 8], 1);
            skey[pos] = (ed.x << 8) | (ed.y & 255);
        }
        __syncthreads();
        for (int w = 0; w < ne; w += 256) {
            int e = w + t;
            if (e < ne) {
                unsigned int k = skey[e];
                int pos = atomicAdd(&ccur[k & 255], 1);
                col[pos] = (int)(k >> 8);
            }
            __syncthreads();
        }
    } else {
        for (int e = t; e < ne; e += 256) {
            uint2 ed = ebuf[base + e];
            int pos = atomicAdd(&ccur[ed.y & 255], 1);
            col[pos] = (int)ed.x;
        }
        __syncthreads();
    }
    int node0 = b * 256;
    #pragma unroll
    for (int it = 0; it < 16; it++) {
        int nl = it * 16 + (t >> 4);
        int gn = node0 + nl;
        if (gn >= N) continue;
        float d2 = sdinv[nl];
        int fo = (t & 15) << 3;
        u16x8 v = *(const u16x8*)(xbf + (size_t)gn * FIN + fo);
        u16x8 o;
        #pragma unroll
        for (int j = 0; j < 8; j++) o[j] = f2bf(d2 * bf2f(v[j]));
        *(u16x8*)(xs + (size_t)gn * FIN + fo) = o;
    }
}

// ---------------------------------------------------------------------------
// MFMA bf16 GEMM with LDS-bounce coalesced epilogue.
// C[M,Ncol] = A[M,K] @ B (BT stored [Ncol,K] bf16); grid.x==1, CF=Ncol/16.
template <int CF, int CBF, int RELU, int SCALE>
__global__ __launch_bounds__(256) void mfma_gemm(
    const unsigned short* __restrict__ A, const unsigned short* __restrict__ BT,
    const float* __restrict__ bias, const float* __restrict__ rowscale,
    void* __restrict__ Cv, int M, int Ncol, int K)
{
    constexpr int ESZ  = CBF ? 2 : 4;
    constexpr int ROWB = CF * 16 * ESZ + 16;     // padded row bytes (16B mult)
    __shared__ __align__(16) unsigned char eplds[4 * 16 * ROWB];

    const int lane = threadIdx.x & 63;
    const int wave = threadIdx.x >> 6;
    const int m = lane & 15;
    const int q = lane >> 4;
    const int rowbase = blockIdx.y * 64 + wave * 16;
    const int row = rowbase + m;

    f32x4 acc[CF] = {};

    const unsigned short* arow = A + (size_t)row * K + q * 8;
    const unsigned short* brow = BT + (size_t)m * K + q * 8;

    for (int k0 = 0; k0 < K; k0 += 32) {
        bf16x8 a = {};
        if (row < M) a = *(const bf16x8*)(arow + k0);
        #pragma unroll
        for (int c = 0; c < CF; c++) {
            bf16x8 b = *(const bf16x8*)(brow + (size_t)c * 16 * K + k0);
            acc[c] = __builtin_amdgcn_mfma_f32_16x16x32_bf16(a, b, acc[c], 0, 0, 0);
        }
    }

    float rs[4];
    #pragma unroll
    for (int r = 0; r < 4; r++) {
        int gr = rowbase + q * 4 + r;
        rs[r] = (SCALE && gr < M) ? rowscale[gr] : 1.0f;
    }

    unsigned char* wbase = eplds + wave * 16 * ROWB;
    #pragma unroll
    for (int c = 0; c < CF; c++) {
        int gc = c * 16 + m;
        float bv = bias ? bias[gc] : 0.0f;
        #pragma unroll
        for (int r = 0; r < 4; r++) {
            float v = acc[c][r] + bv;
            if (SCALE) v *= rs[r];
            if (RELU) v = fmaxf(v, 0.f);
            if (CBF) ((unsigned short*)(wbase + (q * 4 + r) * ROWB))[gc] = f2bf(v);
            else     ((float*)(wbase + (q * 4 + r) * ROWB))[gc] = v;
        }
    }
    // coalesced read-out: 16B per lane (wave-private region, no barrier needed)
    constexpr int LPR = CF * ESZ;        // lanes per row
    constexpr int RPP = 64 / LPR;        // rows per pass
    constexpr int NP  = 16 / RPP;        // passes
    #pragma unroll
    for (int p = 0; p < NP; p++) {
        int r2 = p * RPP + lane / LPR;
        int bo = (lane % LPR) * 16;
        int gr = rowbase + r2;
        if (gr < M) {
            uint4 v = *(const uint4*)(wbase + r2 * ROWB + bo);
            *(uint4*)((unsigned char*)Cv + (size_t)gr * Ncol * ESZ + bo) = v;
        }
    }
}

// ---------------------------------------------------------------------------
// Fused MLP: xfc = relu(x@Wf1+bf1)@Wf2 + bf2.  Per-wave f1 tile lives in LDS
// (each wave consumes exactly the 16 rows it produced -> no cross-wave sync).
__global__ __launch_bounds__(256) void fused_mlp_kernel(
    const unsigned short* __restrict__ xbf, const unsigned short* __restrict__ wf1t,
    const unsigned short* __restrict__ wf2t, const float* __restrict__ bf1,
    const float* __restrict__ bf2, float* __restrict__ xfc, int M)
{
    __shared__ __align__(16) unsigned short f1lds[4][16][264];  // 264 = 256+8 pad

    const int lane = threadIdx.x & 63;
    const int wave = threadIdx.x >> 6;
    const int m = lane & 15;
    const int q = lane >> 4;
    const int rowbase = blockIdx.x * 64 + wave * 16;
    const int row = rowbase + m;

    // stage 1: f1 = relu(x@Wf1+bf1), 16 rows x 256 cols per wave
    {
        f32x4 acc[16] = {};
        const unsigned short* arow = xbf + (size_t)row * FIN + q * 8;
        const unsigned short* brow = wf1t + (size_t)m * FIN + q * 8;
        for (int k0 = 0; k0 < FIN; k0 += 32) {
            bf16x8 a = {};
            if (row < M) a = *(const bf16x8*)(arow + k0);
            #pragma unroll
            for (int c = 0; c < 16; c++) {
                bf16x8 b = *(const bf16x8*)(brow + (size_t)c * 16 * FIN + k0);
                acc[c] = __builtin_amdgcn_mfma_f32_16x16x32_bf16(a, b, acc[c], 0, 0, 0);
            }
        }
        #pragma unroll
        for (int c = 0; c < 16; c++) {
            int gc = c * 16 + m;
            float bv = bf1[gc];
            #pragma unroll
            for (int r = 0; r < 4; r++) {
                float v = fmaxf(acc[c][r] + bv, 0.f);
                f1lds[wave][q * 4 + r][gc] = f2bf(v);
            }
        }
    }
    // stage 2: xfc = f1@Wf2 + bf2, K=256, A-fragments from LDS
    f32x4 acc2[4] = {};
    {
        const unsigned short* brow = wf2t + (size_t)m * FFC + q * 8;
        for (int k0 = 0; k0 < FFC; k0 += 32) {
            bf16x8 a = *(const bf16x8*)&f1lds[wave][m][k0 + q * 8];
            #pragma unroll
            for (int c = 0; c < 4; c++) {
                bf16x8 b = *(const bf16x8*)(brow + (size_t)c * 16 * FFC + k0);
                acc2[c] = __builtin_amdgcn_mfma_f32_16x16x32_bf16(a, b, acc2[c], 0, 0, 0);
            }
        }
    }
    // epilogue: LDS bounce (reuse wave's region), coalesced float4 stores
    float* xlds = (float*)&f1lds[wave][0][0];   // stride 68 floats (272B, 16B mult)
    #pragma unroll
    for (int c = 0; c < 4; c++) {
        int gc = c * 16 + m;
        float bv = bf2[gc];
        #pragma unroll
        for (int r = 0; r < 4; r++)
            xlds[(q * 4 + r) * 68 + gc] = acc2[c][r] + bv;
    }
    #pragma unroll
    for (int p = 0; p < 4; p++) {
        int r2 = p * 4 + (lane >> 4);
        int cb = (lane & 15) * 4;
        int gr = rowbase + r2;
        if (gr < M) {
            float4 v = *(const float4*)&xlds[r2 * 68 + cb];
            *(float4*)(xfc + (size_t)gr * FOUT + cb) = v;
        }
    }
}

// ---------------------------------------------------------------------------
// CSR pull, F=128, pre-scaled rows, src-sorted lists:
// aggx[i] = di*(xs[i] + sum_s xs[s]).  16 lanes/node, 16B/lane, 4x unroll.
__global__ __launch_bounds__(256) void pull1_kernel(
    const unsigned short* __restrict__ xs, const int* __restrict__ rp,
    const int* __restrict__ col, const float* __restrict__ dinv,
    unsigned short* __restrict__ aggx, int N)
{
    int tid = threadIdx.x;
    int node = blockIdx.x * 16 + (tid >> 4);
    if (node >= N) return;
    int f0 = (tid & 15) << 3;
    const unsigned short* base = xs + f0;
    u16x8 own = *(const u16x8*)(base + (size_t)node * FIN);
    float acc[8];
    #pragma unroll
    for (int j = 0; j < 8; j++) acc[j] = bf2f(own[j]);
    int e = node ? rp[node - 1] : 0;
    int end = rp[node];
    for (; e + 4 <= end; e += 4) {
        int s0 = col[e], s1 = col[e + 1], s2 = col[e + 2], s3 = col[e + 3];
        u16x8 v0 = *(const u16x8*)(base + (size_t)s0 * FIN);
        u16x8 v1 = *(const u16x8*)(base + (size_t)s1 * FIN);
        u16x8 v2 = *(const u16x8*)(base + (size_t)s2 * FIN);
        u16x8 v3 = *(const u16x8*)(base + (size_t)s3 * FIN);
        #pragma unroll
        for (int j = 0; j < 8; j++)
            acc[j] += (bf2f(v0[j]) + bf2f(v1[j])) + (bf2f(v2[j]) + bf2f(v3[j]));
    }
    for (; e < end; e++) {
        u16x8 v = *(const u16x8*)(base + (size_t)col[e] * FIN);
        #pragma unroll
        for (int j = 0; j < 8; j++) acc[j] += bf2f(v[j]);
    }
    float di = dinv[node];
    u16x8 o;
    #pragma unroll
    for (int j = 0; j < 8; j++) o[j] = f2bf(di * acc[j]);
    *(u16x8*)(aggx + (size_t)node * FIN + f0) = o;
}

// CSR pull, F=64, pre-scaled rows, fused bias+blend; bf16 z out.
__global__ __launch_bounds__(256) void pull2_kernel(
    const unsigned short* __restrict__ t2s, const int* __restrict__ rp,
    const int* __restrict__ col, const float* __restrict__ dinv,
    const float* __restrict__ xfc, const float* __restrict__ b2,
    unsigned short* __restrict__ zbf, int N)
{
    int tid = threadIdx.x;
    int node = blockIdx.x * 32 + (tid >> 3);
    if (node >= N) return;
    int f0 = (tid & 7) << 3;
    const unsigned short* base = t2s + f0;
    u16x8 own = *(const u16x8*)(base + (size_t)node * FOUT);
    float acc[8];
    #pragma unroll
    for (int j = 0; j < 8; j++) acc[j] = bf2f(own[j]);
    int e = node ? rp[node - 1] : 0;
    int end = rp[node];
    for (; e + 4 <= end; e += 4) {
        int s0 = col[e], s1 = col[e + 1], s2 = col[e + 2], s3 = col[e + 3];
        u16x8 v0 = *(const u16x8*)(base + (size_t)s0 * FOUT);
        u16x8 v1 = *(const u16x8*)(base + (size_t)s1 * FOUT);
        u16x8 v2 = *(const u16x8*)(base + (size_t)s2 * FOUT);
        u16x8 v3 = *(const u16x8*)(base + (size_t)s3 * FOUT);
        #pragma unroll
        for (int j = 0; j < 8; j++)
            acc[j] += (bf2f(v0[j]) + bf2f(v1[j])) + (bf2f(v2[j]) + bf2f(v3[j]));
    }
    for (; e < end; e++) {
        u16x8 v = *(const u16x8*)(base + (size_t)col[e] * FOUT);
        #pragma unroll
        for (int j = 0; j < 8; j++) acc[j] += bf2f(v[j]);
    }
    float di = dinv[node];
    float4 x0 = *(const float4*)(xfc + (size_t)node * FOUT + f0);
    float4 x1 = *(const float4*)(xfc + (size_t)node * FOUT + f0 + 4);
    float4 bb0 = *(const float4*)(b2 + f0);
    float4 bb1 = *(const float4*)(b2 + f0 + 4);
    float xf[8] = { x0.x, x0.y, x0.z, x0.w, x1.x, x1.y, x1.z, x1.w };
    float bv[8] = { bb0.x, bb0.y, bb0.z, bb0.w, bb1.x, bb1.y, bb1.z, bb1.w };
    u16x8 o;
    #pragma unroll
    for (int j = 0; j < 8; j++)
        o[j] = f2bf(0.5f * (di * acc[j] + bv[j]) + 0.5f * xf[j]);
    *(u16x8*)(zbf + (size_t)node * FOUT + f0) = o;
}

// out[q] = dot(z[a], z[b]) over 64 dims; 8 threads/query, 16B bf16 each.
__global__ void decode_kernel(
    const unsigned short* __restrict__ zbf, const int* __restrict__ eli,
    float* __restrict__ out, int Q)
{
    int tid = blockIdx.x * blockDim.x + threadIdx.x;
    int q = tid >> 3;
    if (q >= Q) return;
    int lane = tid & 7;
    int a = eli[q];
    int b = eli[Q + q];
    u16x8 va = *(const u16x8*)(zbf + (size_t)a * FOUT + lane * 8);
    u16x8 vb = *(const u16x8*)(zbf + (size_t)b * FOUT + lane * 8);
    float s = 0.f;
    #pragma unroll
    for (int j = 0; j < 8; j++) s += bf2f(va[j]) * bf2f(vb[j]);
    s += __shfl_down(s, 4, 8);
    s += __shfl_down(s, 2, 8);
    s += __shfl_down(s, 1, 8);
    if (lane == 0) out[q] = s;
}

// ---------------------------------------------------------------------------
extern "C" void kernel_launch(void* const* d_in, const int* in_sizes, int n_in,
                              void* d_out, int out_size, void* d_ws, size_t ws_size,
                              hipStream_t stream)
{
    const float* x   = (const float*)d_in[0];
    const int*   ei  = (const int*)  d_in[1];
    const int*   eli = (const int*)  d_in[2];
    const float* W1  = (const float*)d_in[3];
    const float* b1  = (const float*)d_in[4];
    const float* W2  = (const float*)d_in[5];
    const float* b2  = (const float*)d_in[6];
    const float* Wf1 = (const float*)d_in[7];
    const float* bf1 = (const float*)d_in[8];
    const float* Wf2 = (const float*)d_in[9];
    const float* bf2 = (const float*)d_in[10];
    float* out = (float*)d_out;

    const int N = in_sizes[0] / FIN;       // 50000
    const int E = in_sizes[1] / 2;         // 1600000
    const int Q = in_sizes[2] / 2;         // 500000
    const int* src = ei;
    const int* dst = ei + E;
    const int NBK = (N + 255) >> 8;        // 196 buckets

    // Workspace layout (bytes; 16B-aligned). Peak ~58 MB.
    char* p = (char*)d_ws;
    float* dinv  = (float*)p;            p += (size_t)N * 4;
    int*   rp    = (int*)p;              p += (size_t)(N + 4) * 4;
    int*   bhist = (int*)p;              p += 1024;
    int*   bbase = (int*)p;              p += 1024;
    int*   bcur  = (int*)p;              p += 1024;
    int*   col   = (int*)p;              p += (size_t)E * 4;
    unsigned short* xbf  = (unsigned short*)p; p += (size_t)N * FIN * 2;
    unsigned short* w1t  = (unsigned short*)p; p += FIN * FHID * 2;
    unsigned short* w2t  = (unsigned short*)p; p += FHID * FOUT * 2;
    unsigned short* wf1t = (unsigned short*)p; p += FIN * FFC * 2;
    unsigned short* wf2t = (unsigned short*)p; p += FFC * FOUT * 2;
    float* xfc = (float*)p;              p += (size_t)N * FOUT * 4;
    char*  S   = p;
    unsigned short* xs   = (unsigned short*)S;
    uint2*          ebuf = (uint2*)(S + (size_t)N * FIN * 2);
    unsigned short* aggx = (unsigned short*)(S + (size_t)N * FIN * 2);
    unsigned short* h1   = (unsigned short*)S;
    unsigned short* t2s  = (unsigned short*)(S + (size_t)N * FIN * 2);
    unsigned short* zbf  = (unsigned short*)(S + (size_t)N * FIN * 2
                                               + (size_t)N * FOUT * 2);

    const int TB = 256;

    // --- converts ---
    {
        long n4 = (long)N * FIN / 4;
        cvt_bf16_kernel<<<(n4 + TB - 1) / TB, TB, 0, stream>>>(x, xbf, n4);
    }
    cvt_weights_kernel<<<(73728 + TB - 1) / TB, TB, 0, stream>>>(
        W1, W2, Wf1, Wf2, w1t, w2t, wf1t, wf2t);

    // --- FC path: one fused kernel, no f1 round-trip ---
    fused_mlp_kernel<<<(N + 63) / 64, TB, 0, stream>>>(
        xbf, wf1t, wf2t, bf1, bf2, xfc, N);

    // --- bucketed CSR build (+ coarse src-sort + fused dinv & xs scaling) ---
    hipMemsetAsync(bhist, 0, 1024, stream);
    hist_kernel<<<1024, TB, 0, stream>>>(dst, bhist, E, NBK);
    bscan_kernel<<<1, TB, 0, stream>>>(bhist, bbase, bcur, NBK);
    binA_kernel<<<(E + CHUNK - 1) / CHUNK, TB, 0, stream>>>(src, dst, bcur, ebuf, E, NBK);
    binB_kernel<<<NBK, TB, 0, stream>>>(ebuf, bbase, bhist, rp, col, dinv, xbf, xs, N);

    // --- GCN layer 1: aggx = dinv*(xs + sum xs); h1 = relu(aggx@W1+b1) ---
    pull1_kernel<<<(N + 15) / 16, TB, 0, stream>>>(xs, rp, col, dinv, aggx, N);
    {
        dim3 g(1, (N + 63) / 64);
        mfma_gemm<8, 1, 1, 0><<<g, TB, 0, stream>>>(aggx, w1t, b1, nullptr, h1, N, FHID, FIN);
    }

    // --- GCN layer 2: t2s = dinv*(h1@W2) [bf16]; z = 0.5*(dinv*agg+b2)+0.5*xfc ---
    {
        dim3 g(1, (N + 63) / 64);
        mfma_gemm<4, 1, 0, 1><<<g, TB, 0, stream>>>(h1, w2t, nullptr, dinv, t2s, N, FOUT, FHID);
    }
    pull2_kernel<<<(N + 31) / 32, TB, 0, stream>>>(t2s, rp, col, dinv, xfc, b2, zbf, N);

    // --- decode ---
    {
        long total = (long)Q * 8;
        decode_kernel<<<(total + TB - 1) / TB, TB, 0, stream>>>(zbf, eli, out, Q);
    }
}